// Round 6
// baseline (493.495 us; speedup 1.0000x reference)
//
#include <hip/hip_runtime.h>

// Two kernels, no setup kernel, no weight blob.
// K1 conv (v6 = v5 with the occupancy cap removed): lane = 8*c + g (c =
//   channel 0..7, g = node-group 0..7); each lane owns channel c of nodes
//   {g+8s}, s=0..3. Weights register-resident (48 floats/lane, amortized
//   over NB=4 batches). Per batch (2KB = 128 float4): wave stages x into LDS
//   with 2 fully-coalesced dwordx4 loads per lane (prefetched one batch
//   ahead), node stride XSTR=20 -> ds_read_b128 g-windows disjoint mod 32 =
//   conflict-free; channel-duplicate lanes broadcast (free). Node numbering
//   n=g+8s makes h-transpose reads (HPAD=12) conflict-free (12g%32
//   distinct). Reductions: local serial + one 3-stage xor-butterfly per
//   tree serving all 8 channels. Star fold: leaves' agg is the wave-uniform
//   m[node0] vector via tiny LDS scr exchange. Same-wave LDS write->read
//   (no barriers) is in-order in the DS pipe (validated rounds 3/5).
//   v5 post-mortem: VALU-time ~30us but VALUBusy 31% / Occ 28.7% -- the
//   (256,3) bound capped residency at 12 waves/CU, leaving the serial DS
//   chain exposed. (256,6) -> 24 waves/CU (VGPR 68 <= 85 cap, LDS 101KB/CU).
//   Writes res[B][16] = {sum_h[8], sum_agg2[8]} to d_ws.
// K2 mlp: unchanged known-good version. block = 64 batches x 4 waves, wave p
//   computes out-slice [16p,16p+16); pooled = (res@[Ws2|Wn2])/32 + bc2.

typedef float v2f __attribute__((ext_vector_type(2)));
__device__ __forceinline__ v2f fma2(v2f a, v2f b, v2f c) {
  return __builtin_elementwise_fma(a, b, c);
}
__device__ __forceinline__ v2f ld2(const float* p) { return *(const v2f*)p; }

__device__ __forceinline__ float fast_tanh(float v) {
  v = fminf(fmaxf(v, -10.f), 10.f);
  float e = exp2f(v * 2.8853900817779268f);          // e^(2v)
  return 1.f - 2.f * __builtin_amdgcn_rcpf(e + 1.f); // (e-1)/(e+1)
}

// ds_swizzle BitMode xor-butterfly within 8-lane blocks (and=0x1F keeps it
// inside 32-lane halves; xor masks 1,2,4 never cross an 8-block).
template<int OFF>
__device__ __forceinline__ float swz(float v) {
  return __int_as_float(__builtin_amdgcn_ds_swizzle(__float_as_int(v), OFF));
}
__device__ __forceinline__ float bflymax8(float t) {
  t = fmaxf(t, swz<0x041F>(t));  // xor 1
  t = fmaxf(t, swz<0x081F>(t));  // xor 2
  t = fmaxf(t, swz<0x101F>(t));  // xor 4
  return t;
}
__device__ __forceinline__ float bflysum8(float t) {
  t += swz<0x041F>(t);
  t += swz<0x081F>(t);
  t += swz<0x101F>(t);
  return t;
}

// ===================== K1: conv1 + conv2 + per-batch pooling ================
#define NB 4     // batches per wave
#define XSTR 20  // x-stage node stride (floats): 20g%32 distinct, 16B-aligned
#define HPAD 12  // h-transpose node stride: 12g%32 distinct, 16B-aligned
#define WREG (32*XSTR + 32*HPAD + 16)  // 1040 floats per wave
__global__ __launch_bounds__(256, 6) void conv_kernel(
    const float* __restrict__ x,
    const float* __restrict__ Wp1, const float* __restrict__ bp1,
    const float* __restrict__ Ws1, const float* __restrict__ Wn1,
    const float* __restrict__ bc1,
    const float* __restrict__ Wp2, const float* __restrict__ bp2,
    float* __restrict__ res) {
  __shared__ __align__(16) float lds[4 * WREG];
  const int tid  = threadIdx.x;
  const int wid  = tid >> 6;
  const int lane = tid & 63;
  const int c    = lane >> 3;     // channel 0..7
  const int g    = lane & 7;      // node-group: nodes g+8s, s=0..3
  const bool g0  = (g == 0);      // slot 0 of g==0 is node0
  float* xs  = lds + wid * WREG;  // [32 nodes][XSTR]
  float* hs  = xs + 32 * XSTR;    // [32 nodes][HPAD]
  float* scr = hs + 32 * HPAD;    // [16]

  // ---- weight preload: column c, register-resident for all NB batches ----
  float wp1[16], ws1[16], wn1[8], wp2[8];
  #pragma unroll
  for (int f = 0; f < 16; f++) { wp1[f] = Wp1[f*8 + c]; ws1[f] = Ws1[f*8 + c]; }
  #pragma unroll
  for (int j = 0; j < 8; j++)  { wn1[j] = Wn1[j*8 + c]; wp2[j] = Wp2[j*8 + c]; }
  const float bp1c = bp1[c], bc1c = bc1[c], bp2c = bp2[c];

  const int b0 = (blockIdx.x * 4 + wid) * NB;
  const float4* xg = (const float4*)x;      // 128 float4 per batch (2KB)
  size_t gb = (size_t)b0 * 128 + lane;

  // prefetch batch b0 (coalesced: lane + 64k, k<2)
  float4 xf[2];
  #pragma unroll
  for (int k = 0; k < 2; k++) xf[k] = xg[gb + 64*k];

  #pragma unroll 1
  for (int it = 0; it < NB; ++it) {
    const int b = b0 + it;

    // stage x to LDS: float4 j = lane+64k -> node j>>2 (0..31), quad j&3;
    // write banks (20n+4q)%32: n and n+8 alias -> 2-way (free)
    #pragma unroll
    for (int k = 0; k < 2; k++) {
      const int j = lane + 64*k;
      *(float4*)(xs + (j >> 2) * XSTR + 4*(j & 3)) = xf[k];
    }
    // prefetch next batch while this one computes
    if (it + 1 < NB) {
      gb += 128;
      #pragma unroll
      for (int k = 0; k < 2; k++) xf[k] = xg[gb + 64*k];
    }

    // conv1 for own 4 nodes (channel c): m=relu(x.wp1+b), sv=x.ws1+b
    float m[4], sv[4];
    #pragma unroll
    for (int s = 0; s < 4; s++) {
      const float* xn = xs + (g + 8*s) * XSTR;   // start bank 20g%32: distinct
      float4 X0 = *(const float4*)(xn);
      float4 X1 = *(const float4*)(xn + 4);
      float4 X2 = *(const float4*)(xn + 8);
      float4 X3 = *(const float4*)(xn + 12);
      float xfl[16] = {X0.x,X0.y,X0.z,X0.w, X1.x,X1.y,X1.z,X1.w,
                       X2.x,X2.y,X2.z,X2.w, X3.x,X3.y,X3.z,X3.w};
      float mm = bp1c, ss = bc1c;
      #pragma unroll
      for (int f = 0; f < 16; f++) {
        mm = fmaf(xfl[f], wp1[f], mm);
        ss = fmaf(xfl[f], ws1[f], ss);
      }
      m[s]  = fmaxf(mm, 0.f);
      sv[s] = ss;
    }

    // max over leaves (own channel): exclude node0 (slot 0 at g==0)
    float lm = g0 ? fmaxf(fmaxf(m[1], m[2]), m[3])
                  : fmaxf(fmaxf(m[0], m[1]), fmaxf(m[2], m[3]));
    lm = bflymax8(lm);

    // gather {m0_c, maxleaves_c} across channels via tiny LDS scratch
    if (g0) *(v2f*)(scr + 2*c) = (v2f){m[0], lm};
    float4 q0 = *(const float4*)(scr + 0);
    float4 q1 = *(const float4*)(scr + 4);
    float4 q2 = *(const float4*)(scr + 8);
    float4 q3 = *(const float4*)(scr + 12);
    float m0v[8] = {q0.x,q0.z, q1.x,q1.z, q2.x,q2.z, q3.x,q3.z};
    float mlv[8] = {q0.y,q0.w, q1.y,q1.w, q2.y,q2.w, q3.y,q3.w};

    // star fold: every leaf's agg = m0v (wave-uniform); node0's agg = mlv
    float leafdot = 0.f, zerodot = 0.f;
    #pragma unroll
    for (int j = 0; j < 8; j++) {
      leafdot = fmaf(m0v[j], wn1[j], leafdot);
      zerodot = fmaf(mlv[j], wn1[j], zerodot);
    }
    float h0 = fast_tanh(sv[0] + (g0 ? zerodot : leafdot));  // node g (0 if g0)
    float h1 = fast_tanh(sv[1] + leafdot);
    float h2 = fast_tanh(sv[2] + leafdot);
    float h3 = fast_tanh(sv[3] + leafdot);

    // h transpose via LDS: hs[n*HPAD + c]; write banks (12g+c)%32 <=2-way
    hs[(g +  0)*HPAD + c] = h0;
    hs[(g +  8)*HPAD + c] = h1;
    hs[(g + 16)*HPAD + c] = h2;
    hs[(g + 24)*HPAD + c] = h3;

    // conv2 pool-proj: m2[s] = relu(h_n . wp2 + bp2c); reads conflict-free
    float m2[4];
    #pragma unroll
    for (int s = 0; s < 4; s++) {
      const float* hn = hs + (g + 8*s) * HPAD;   // start bank 12g%32: distinct
      float4 ha = *(const float4*)(hn);
      float4 hb = *(const float4*)(hn + 4);
      float mm = bp2c;
      mm = fmaf(ha.x, wp2[0], mm); mm = fmaf(ha.y, wp2[1], mm);
      mm = fmaf(ha.z, wp2[2], mm); mm = fmaf(ha.w, wp2[3], mm);
      mm = fmaf(hb.x, wp2[4], mm); mm = fmaf(hb.y, wp2[5], mm);
      mm = fmaf(hb.z, wp2[6], mm); mm = fmaf(hb.w, wp2[7], mm);
      m2[s] = fmaxf(mm, 0.f);
    }

    // per-batch outputs (one butterfly serves all channels)
    float sh = bflysum8((h0 + h1) + (h2 + h3));          // sum_n h_c
    float lm2 = g0 ? fmaxf(fmaxf(m2[1], m2[2]), m2[3])
                   : fmaxf(fmaxf(m2[0], m2[1]), fmaxf(m2[2], m2[3]));
    lm2 = bflymax8(lm2);                                 // max over leaves' m2
    if (g0) {
      res[(size_t)b*16 + c]     = sh;
      res[(size_t)b*16 + 8 + c] = fmaf(31.f, m2[0], lm2); // + 31*m2[node0]
    }
  }
}

// ===================== K2: pooled fold + 4-layer MLP ========================
#define HSTR 65  // LDS row stride: (l*65+k)%32 distinct over 32 lanes; 2-way=free
__global__ __launch_bounds__(256, 3) void mlp_kernel(
    const float* __restrict__ res, const float* __restrict__ obs,
    const float* __restrict__ Ws2, const float* __restrict__ Wn2,
    const float* __restrict__ bc2,
    const float* __restrict__ W1, const float* __restrict__ bf1,
    const float* __restrict__ W2, const float* __restrict__ bf2,
    const float* __restrict__ W3, const float* __restrict__ bf3,
    const float* __restrict__ W4, const float* __restrict__ bf4,
    float* __restrict__ out) {
  __shared__ float hx[64 * HSTR];
  const int tid  = threadIdx.x;
  const int lane = tid & 63;                                  // batch in block
  const int p    = __builtin_amdgcn_readfirstlane(tid >> 6);  // out-slice wave
  const int b    = blockIdx.x * 64 + lane;
  const int ob0  = p * 16;

  const float4* rp = (const float4*)(res + (size_t)b * 16);
  float4 r0 = rp[0], r1 = rp[1], r2 = rp[2], r3 = rp[3];
  const float4* op = (const float4*)(obs + (size_t)b * 16);
  float4 o0 = op[0], o1 = op[1], o2 = op[2], o3 = op[3];
  float rm[8] = {r0.x,r0.y,r0.z,r0.w, r1.x,r1.y,r1.z,r1.w};
  float ag[8] = {r2.x,r2.y,r2.z,r2.w, r3.x,r3.y,r3.z,r3.w};
  float ob[16] = {o0.x,o0.y,o0.z,o0.w, o1.x,o1.y,o1.z,o1.w,
                  o2.x,o2.y,o2.z,o2.w, o3.x,o3.y,o3.z,o3.w};

  // pooled = (sumh@Ws2 + sumagg2@Wn2)/32 + bc2
  v2f pv[4];
  #pragma unroll
  for (int i = 0; i < 4; i++) pv[i] = (v2f){0.f, 0.f};
  #pragma unroll
  for (int j = 0; j < 8; j++) {
    v2f rv = {rm[j], rm[j]}, av = {ag[j], ag[j]};
    #pragma unroll
    for (int i = 0; i < 4; i++) {
      pv[i] = fma2(rv, ld2(Ws2 + j*8 + 2*i), pv[i]);
      pv[i] = fma2(av, ld2(Wn2 + j*8 + 2*i), pv[i]);
    }
  }
  float pooled[8];
  #pragma unroll
  for (int i = 0; i < 4; i++) {
    pooled[2*i]   = fmaf(pv[i].x, 1.f/32.f, bc2[2*i]);
    pooled[2*i+1] = fmaf(pv[i].y, 1.f/32.f, bc2[2*i+1]);
  }

  v2f acc[8];
  // ---- layer 1: [pooled | obs] @ W1 + bf1, slice [ob0, ob0+16) ----
  #pragma unroll
  for (int i = 0; i < 8; i++) acc[i] = ld2(bf1 + ob0 + 2*i);
  #pragma unroll
  for (int j = 0; j < 8; j++) {
    v2f sj = {pooled[j], pooled[j]};
    #pragma unroll
    for (int i = 0; i < 8; i++) acc[i] = fma2(sj, ld2(W1 + j*64 + ob0 + 2*i), acc[i]);
  }
  #pragma unroll
  for (int j = 0; j < 16; j++) {
    v2f sj = {ob[j], ob[j]};
    #pragma unroll
    for (int i = 0; i < 8; i++) acc[i] = fma2(sj, ld2(W1 + (8+j)*64 + ob0 + 2*i), acc[i]);
  }
  #pragma unroll
  for (int i = 0; i < 8; i++) {
    hx[lane*HSTR + ob0 + 2*i]   = fmaxf(acc[i].x, 0.f);
    hx[lane*HSTR + ob0 + 2*i+1] = fmaxf(acc[i].y, 0.f);
  }
  __syncthreads();
  float h[64];
  #pragma unroll
  for (int k = 0; k < 64; k++) h[k] = hx[lane*HSTR + k];
  __syncthreads();

  // ---- layer 2 ----
  #pragma unroll
  for (int i = 0; i < 8; i++) acc[i] = ld2(bf2 + ob0 + 2*i);
  #pragma unroll
  for (int k = 0; k < 64; k++) {
    v2f hk = {h[k], h[k]};
    #pragma unroll
    for (int i = 0; i < 8; i++) acc[i] = fma2(hk, ld2(W2 + k*64 + ob0 + 2*i), acc[i]);
  }
  #pragma unroll
  for (int i = 0; i < 8; i++) {
    hx[lane*HSTR + ob0 + 2*i]   = fmaxf(acc[i].x, 0.f);
    hx[lane*HSTR + ob0 + 2*i+1] = fmaxf(acc[i].y, 0.f);
  }
  __syncthreads();
  #pragma unroll
  for (int k = 0; k < 64; k++) h[k] = hx[lane*HSTR + k];
  __syncthreads();

  // ---- layer 3 ----
  #pragma unroll
  for (int i = 0; i < 8; i++) acc[i] = ld2(bf3 + ob0 + 2*i);
  #pragma unroll
  for (int k = 0; k < 64; k++) {
    v2f hk = {h[k], h[k]};
    #pragma unroll
    for (int i = 0; i < 8; i++) acc[i] = fma2(hk, ld2(W3 + k*64 + ob0 + 2*i), acc[i]);
  }
  #pragma unroll
  for (int i = 0; i < 8; i++) {
    hx[lane*HSTR + ob0 + 2*i]   = fmaxf(acc[i].x, 0.f);
    hx[lane*HSTR + ob0 + 2*i+1] = fmaxf(acc[i].y, 0.f);
  }
  __syncthreads();

  // ---- layer 4 + tanh (wave 0 only) ----
  if (p == 0) {
    #pragma unroll
    for (int k = 0; k < 64; k++) h[k] = hx[lane*HSTR + k];
    v2f o4a = ld2(bf4), o4b = ld2(bf4 + 2);
    #pragma unroll
    for (int k = 0; k < 64; k++) {
      v2f hk = {h[k], h[k]};
      o4a = fma2(hk, ld2(W4 + k*4),     o4a);
      o4b = fma2(hk, ld2(W4 + k*4 + 2), o4b);
    }
    ((float4*)out)[b] = make_float4(fast_tanh(o4a.x), fast_tanh(o4a.y),
                                    fast_tanh(o4b.x), fast_tanh(o4b.y));
  }
}

extern "C" void kernel_launch(void* const* d_in, const int* in_sizes, int n_in,
                              void* d_out, int out_size, void* d_ws, size_t ws_size,
                              hipStream_t stream) {
  const float* x   = (const float*)d_in[0];
  const float* obs = (const float*)d_in[1];
  // d_in[2..4] = src/dst/node_seg: fixed star graph, exploited structurally
  const float* Wp1 = (const float*)d_in[5];
  const float* bp1 = (const float*)d_in[6];
  const float* Ws1 = (const float*)d_in[7];
  const float* Wn1 = (const float*)d_in[8];
  const float* bc1 = (const float*)d_in[9];
  const float* Wp2 = (const float*)d_in[10];
  const float* bp2 = (const float*)d_in[11];
  const float* Ws2 = (const float*)d_in[12];
  const float* Wn2 = (const float*)d_in[13];
  const float* bc2 = (const float*)d_in[14];
  const float* W1  = (const float*)d_in[15];
  const float* bf1 = (const float*)d_in[16];
  const float* W2  = (const float*)d_in[17];
  const float* bf2 = (const float*)d_in[18];
  const float* W3  = (const float*)d_in[19];
  const float* bf3 = (const float*)d_in[20];
  const float* W4  = (const float*)d_in[21];
  const float* bf4 = (const float*)d_in[22];
  float* res = (float*)d_ws;  // [65536][16] floats = 4 MB
  float* out = (float*)d_out;

  // 65536 batches / (4 waves/block * NB=4 batches/wave) = 4096 blocks
  hipLaunchKernelGGL(conv_kernel, dim3(4096), dim3(256), 0, stream,
                     x, Wp1, bp1, Ws1, Wn1, bc1, Wp2, bp2, res);
  hipLaunchKernelGGL(mlp_kernel, dim3(1024), dim3(256), 0, stream,
                     res, obs, Ws2, Wn2, bc2, W1, bf1, W2, bf2, W3, bf3, W4, bf4, out);
}

// Round 8
// 344.664 us; speedup vs baseline: 1.4318x; 1.4318x over previous
//
#include <hip/hip_runtime.h>

// Two kernels, no setup kernel, no weight blob.
// K1 conv (v7 = v5 with (256,4)): lane = 8*c + g (c = channel 0..7, g =
//   node-group 0..7); each lane owns channel c of nodes {g+8s}, s=0..3.
//   Weights register-resident (48 floats/lane, amortized over NB=4 batches).
//   Per batch (2KB = 128 float4): wave stages x into LDS with 2 fully-
//   coalesced dwordx4 loads per lane (prefetched one batch ahead), node
//   stride XSTR=20 -> ds_read_b128 g-windows disjoint mod 32 = conflict-
//   free; channel-duplicate lanes broadcast (free). Node numbering n=g+8s
//   makes h-transpose reads (HPAD=12) conflict-free (12g%32 distinct).
//   Reductions: local serial + one 3-stage xor-butterfly per tree serving
//   all 8 channels. Star fold: leaves' agg is the wave-uniform m[node0]
//   vector via tiny LDS scr exchange. Same-wave LDS write->read (no
//   barriers) is in-order in the DS pipe (validated rounds 3/5).
//   OCCUPANCY HISTORY: (256,3) -> 9.2 waves/CU, latency-bound, 96us.
//   (256,6) -> compiler crushed VGPR 68->40, ~1GB spill traffic, 274us
//   (gfx950 wave-slot steps are effectively 64/128/256 VGPR). (256,4) is
//   the sweet spot: VGPR cap 128 (no spill), 16 waves/CU.
//   (round 7 was an infra failure -- this is an identical resubmit.)
//   Writes res[B][16] = {sum_h[8], sum_agg2[8]} to d_ws.
// K2 mlp: unchanged known-good version. block = 64 batches x 4 waves, wave p
//   computes out-slice [16p,16p+16); pooled = (res@[Ws2|Wn2])/32 + bc2.

typedef float v2f __attribute__((ext_vector_type(2)));
__device__ __forceinline__ v2f fma2(v2f a, v2f b, v2f c) {
  return __builtin_elementwise_fma(a, b, c);
}
__device__ __forceinline__ v2f ld2(const float* p) { return *(const v2f*)p; }

__device__ __forceinline__ float fast_tanh(float v) {
  v = fminf(fmaxf(v, -10.f), 10.f);
  float e = exp2f(v * 2.8853900817779268f);          // e^(2v)
  return 1.f - 2.f * __builtin_amdgcn_rcpf(e + 1.f); // (e-1)/(e+1)
}

// ds_swizzle BitMode xor-butterfly within 8-lane blocks (and=0x1F keeps it
// inside 32-lane halves; xor masks 1,2,4 never cross an 8-block).
template<int OFF>
__device__ __forceinline__ float swz(float v) {
  return __int_as_float(__builtin_amdgcn_ds_swizzle(__float_as_int(v), OFF));
}
__device__ __forceinline__ float bflymax8(float t) {
  t = fmaxf(t, swz<0x041F>(t));  // xor 1
  t = fmaxf(t, swz<0x081F>(t));  // xor 2
  t = fmaxf(t, swz<0x101F>(t));  // xor 4
  return t;
}
__device__ __forceinline__ float bflysum8(float t) {
  t += swz<0x041F>(t);
  t += swz<0x081F>(t);
  t += swz<0x101F>(t);
  return t;
}

// ===================== K1: conv1 + conv2 + per-batch pooling ================
#define NB 4     // batches per wave
#define XSTR 20  // x-stage node stride (floats): 20g%32 distinct, 16B-aligned
#define HPAD 12  // h-transpose node stride: 12g%32 distinct, 16B-aligned
#define WREG (32*XSTR + 32*HPAD + 16)  // 1040 floats per wave
__global__ __launch_bounds__(256, 4) void conv_kernel(
    const float* __restrict__ x,
    const float* __restrict__ Wp1, const float* __restrict__ bp1,
    const float* __restrict__ Ws1, const float* __restrict__ Wn1,
    const float* __restrict__ bc1,
    const float* __restrict__ Wp2, const float* __restrict__ bp2,
    float* __restrict__ res) {
  __shared__ __align__(16) float lds[4 * WREG];
  const int tid  = threadIdx.x;
  const int wid  = tid >> 6;
  const int lane = tid & 63;
  const int c    = lane >> 3;     // channel 0..7
  const int g    = lane & 7;      // node-group: nodes g+8s, s=0..3
  const bool g0  = (g == 0);      // slot 0 of g==0 is node0
  float* xs  = lds + wid * WREG;  // [32 nodes][XSTR]
  float* hs  = xs + 32 * XSTR;    // [32 nodes][HPAD]
  float* scr = hs + 32 * HPAD;    // [16]

  // ---- weight preload: column c, register-resident for all NB batches ----
  float wp1[16], ws1[16], wn1[8], wp2[8];
  #pragma unroll
  for (int f = 0; f < 16; f++) { wp1[f] = Wp1[f*8 + c]; ws1[f] = Ws1[f*8 + c]; }
  #pragma unroll
  for (int j = 0; j < 8; j++)  { wn1[j] = Wn1[j*8 + c]; wp2[j] = Wp2[j*8 + c]; }
  const float bp1c = bp1[c], bc1c = bc1[c], bp2c = bp2[c];

  const int b0 = (blockIdx.x * 4 + wid) * NB;
  const float4* xg = (const float4*)x;      // 128 float4 per batch (2KB)
  size_t gb = (size_t)b0 * 128 + lane;

  // prefetch batch b0 (coalesced: lane + 64k, k<2)
  float4 xf[2];
  #pragma unroll
  for (int k = 0; k < 2; k++) xf[k] = xg[gb + 64*k];

  #pragma unroll 1
  for (int it = 0; it < NB; ++it) {
    const int b = b0 + it;

    // stage x to LDS: float4 j = lane+64k -> node j>>2 (0..31), quad j&3;
    // write banks (20n+4q)%32: n and n+8 alias -> 2-way (free)
    #pragma unroll
    for (int k = 0; k < 2; k++) {
      const int j = lane + 64*k;
      *(float4*)(xs + (j >> 2) * XSTR + 4*(j & 3)) = xf[k];
    }
    // prefetch next batch while this one computes
    if (it + 1 < NB) {
      gb += 128;
      #pragma unroll
      for (int k = 0; k < 2; k++) xf[k] = xg[gb + 64*k];
    }

    // conv1 for own 4 nodes (channel c): m=relu(x.wp1+b), sv=x.ws1+b
    float m[4], sv[4];
    #pragma unroll
    for (int s = 0; s < 4; s++) {
      const float* xn = xs + (g + 8*s) * XSTR;   // start bank 20g%32: distinct
      float4 X0 = *(const float4*)(xn);
      float4 X1 = *(const float4*)(xn + 4);
      float4 X2 = *(const float4*)(xn + 8);
      float4 X3 = *(const float4*)(xn + 12);
      float xfl[16] = {X0.x,X0.y,X0.z,X0.w, X1.x,X1.y,X1.z,X1.w,
                       X2.x,X2.y,X2.z,X2.w, X3.x,X3.y,X3.z,X3.w};
      float mm = bp1c, ss = bc1c;
      #pragma unroll
      for (int f = 0; f < 16; f++) {
        mm = fmaf(xfl[f], wp1[f], mm);
        ss = fmaf(xfl[f], ws1[f], ss);
      }
      m[s]  = fmaxf(mm, 0.f);
      sv[s] = ss;
    }

    // max over leaves (own channel): exclude node0 (slot 0 at g==0)
    float lm = g0 ? fmaxf(fmaxf(m[1], m[2]), m[3])
                  : fmaxf(fmaxf(m[0], m[1]), fmaxf(m[2], m[3]));
    lm = bflymax8(lm);

    // gather {m0_c, maxleaves_c} across channels via tiny LDS scratch
    if (g0) *(v2f*)(scr + 2*c) = (v2f){m[0], lm};
    float4 q0 = *(const float4*)(scr + 0);
    float4 q1 = *(const float4*)(scr + 4);
    float4 q2 = *(const float4*)(scr + 8);
    float4 q3 = *(const float4*)(scr + 12);
    float m0v[8] = {q0.x,q0.z, q1.x,q1.z, q2.x,q2.z, q3.x,q3.z};
    float mlv[8] = {q0.y,q0.w, q1.y,q1.w, q2.y,q2.w, q3.y,q3.w};

    // star fold: every leaf's agg = m0v (wave-uniform); node0's agg = mlv
    float leafdot = 0.f, zerodot = 0.f;
    #pragma unroll
    for (int j = 0; j < 8; j++) {
      leafdot = fmaf(m0v[j], wn1[j], leafdot);
      zerodot = fmaf(mlv[j], wn1[j], zerodot);
    }
    float h0 = fast_tanh(sv[0] + (g0 ? zerodot : leafdot));  // node g (0 if g0)
    float h1 = fast_tanh(sv[1] + leafdot);
    float h2 = fast_tanh(sv[2] + leafdot);
    float h3 = fast_tanh(sv[3] + leafdot);

    // h transpose via LDS: hs[n*HPAD + c]; write banks (12g+c)%32 <=2-way
    hs[(g +  0)*HPAD + c] = h0;
    hs[(g +  8)*HPAD + c] = h1;
    hs[(g + 16)*HPAD + c] = h2;
    hs[(g + 24)*HPAD + c] = h3;

    // conv2 pool-proj: m2[s] = relu(h_n . wp2 + bp2c); reads conflict-free
    float m2[4];
    #pragma unroll
    for (int s = 0; s < 4; s++) {
      const float* hn = hs + (g + 8*s) * HPAD;   // start bank 12g%32: distinct
      float4 ha = *(const float4*)(hn);
      float4 hb = *(const float4*)(hn + 4);
      float mm = bp2c;
      mm = fmaf(ha.x, wp2[0], mm); mm = fmaf(ha.y, wp2[1], mm);
      mm = fmaf(ha.z, wp2[2], mm); mm = fmaf(ha.w, wp2[3], mm);
      mm = fmaf(hb.x, wp2[4], mm); mm = fmaf(hb.y, wp2[5], mm);
      mm = fmaf(hb.z, wp2[6], mm); mm = fmaf(hb.w, wp2[7], mm);
      m2[s] = fmaxf(mm, 0.f);
    }

    // per-batch outputs (one butterfly serves all channels)
    float sh = bflysum8((h0 + h1) + (h2 + h3));          // sum_n h_c
    float lm2 = g0 ? fmaxf(fmaxf(m2[1], m2[2]), m2[3])
                   : fmaxf(fmaxf(m2[0], m2[1]), fmaxf(m2[2], m2[3]));
    lm2 = bflymax8(lm2);                                 // max over leaves' m2
    if (g0) {
      res[(size_t)b*16 + c]     = sh;
      res[(size_t)b*16 + 8 + c] = fmaf(31.f, m2[0], lm2); // + 31*m2[node0]
    }
  }
}

// ===================== K2: pooled fold + 4-layer MLP ========================
#define HSTR 65  // LDS row stride: (l*65+k)%32 distinct over 32 lanes; 2-way=free
__global__ __launch_bounds__(256, 3) void mlp_kernel(
    const float* __restrict__ res, const float* __restrict__ obs,
    const float* __restrict__ Ws2, const float* __restrict__ Wn2,
    const float* __restrict__ bc2,
    const float* __restrict__ W1, const float* __restrict__ bf1,
    const float* __restrict__ W2, const float* __restrict__ bf2,
    const float* __restrict__ W3, const float* __restrict__ bf3,
    const float* __restrict__ W4, const float* __restrict__ bf4,
    float* __restrict__ out) {
  __shared__ float hx[64 * HSTR];
  const int tid  = threadIdx.x;
  const int lane = tid & 63;                                  // batch in block
  const int p    = __builtin_amdgcn_readfirstlane(tid >> 6);  // out-slice wave
  const int b    = blockIdx.x * 64 + lane;
  const int ob0  = p * 16;

  const float4* rp = (const float4*)(res + (size_t)b * 16);
  float4 r0 = rp[0], r1 = rp[1], r2 = rp[2], r3 = rp[3];
  const float4* op = (const float4*)(obs + (size_t)b * 16);
  float4 o0 = op[0], o1 = op[1], o2 = op[2], o3 = op[3];
  float rm[8] = {r0.x,r0.y,r0.z,r0.w, r1.x,r1.y,r1.z,r1.w};
  float ag[8] = {r2.x,r2.y,r2.z,r2.w, r3.x,r3.y,r3.z,r3.w};
  float ob[16] = {o0.x,o0.y,o0.z,o0.w, o1.x,o1.y,o1.z,o1.w,
                  o2.x,o2.y,o2.z,o2.w, o3.x,o3.y,o3.z,o3.w};

  // pooled = (sumh@Ws2 + sumagg2@Wn2)/32 + bc2
  v2f pv[4];
  #pragma unroll
  for (int i = 0; i < 4; i++) pv[i] = (v2f){0.f, 0.f};
  #pragma unroll
  for (int j = 0; j < 8; j++) {
    v2f rv = {rm[j], rm[j]}, av = {ag[j], ag[j]};
    #pragma unroll
    for (int i = 0; i < 4; i++) {
      pv[i] = fma2(rv, ld2(Ws2 + j*8 + 2*i), pv[i]);
      pv[i] = fma2(av, ld2(Wn2 + j*8 + 2*i), pv[i]);
    }
  }
  float pooled[8];
  #pragma unroll
  for (int i = 0; i < 4; i++) {
    pooled[2*i]   = fmaf(pv[i].x, 1.f/32.f, bc2[2*i]);
    pooled[2*i+1] = fmaf(pv[i].y, 1.f/32.f, bc2[2*i+1]);
  }

  v2f acc[8];
  // ---- layer 1: [pooled | obs] @ W1 + bf1, slice [ob0, ob0+16) ----
  #pragma unroll
  for (int i = 0; i < 8; i++) acc[i] = ld2(bf1 + ob0 + 2*i);
  #pragma unroll
  for (int j = 0; j < 8; j++) {
    v2f sj = {pooled[j], pooled[j]};
    #pragma unroll
    for (int i = 0; i < 8; i++) acc[i] = fma2(sj, ld2(W1 + j*64 + ob0 + 2*i), acc[i]);
  }
  #pragma unroll
  for (int j = 0; j < 16; j++) {
    v2f sj = {ob[j], ob[j]};
    #pragma unroll
    for (int i = 0; i < 8; i++) acc[i] = fma2(sj, ld2(W1 + (8+j)*64 + ob0 + 2*i), acc[i]);
  }
  #pragma unroll
  for (int i = 0; i < 8; i++) {
    hx[lane*HSTR + ob0 + 2*i]   = fmaxf(acc[i].x, 0.f);
    hx[lane*HSTR + ob0 + 2*i+1] = fmaxf(acc[i].y, 0.f);
  }
  __syncthreads();
  float h[64];
  #pragma unroll
  for (int k = 0; k < 64; k++) h[k] = hx[lane*HSTR + k];
  __syncthreads();

  // ---- layer 2 ----
  #pragma unroll
  for (int i = 0; i < 8; i++) acc[i] = ld2(bf2 + ob0 + 2*i);
  #pragma unroll
  for (int k = 0; k < 64; k++) {
    v2f hk = {h[k], h[k]};
    #pragma unroll
    for (int i = 0; i < 8; i++) acc[i] = fma2(hk, ld2(W2 + k*64 + ob0 + 2*i), acc[i]);
  }
  #pragma unroll
  for (int i = 0; i < 8; i++) {
    hx[lane*HSTR + ob0 + 2*i]   = fmaxf(acc[i].x, 0.f);
    hx[lane*HSTR + ob0 + 2*i+1] = fmaxf(acc[i].y, 0.f);
  }
  __syncthreads();
  #pragma unroll
  for (int k = 0; k < 64; k++) h[k] = hx[lane*HSTR + k];
  __syncthreads();

  // ---- layer 3 ----
  #pragma unroll
  for (int i = 0; i < 8; i++) acc[i] = ld2(bf3 + ob0 + 2*i);
  #pragma unroll
  for (int k = 0; k < 64; k++) {
    v2f hk = {h[k], h[k]};
    #pragma unroll
    for (int i = 0; i < 8; i++) acc[i] = fma2(hk, ld2(W3 + k*64 + ob0 + 2*i), acc[i]);
  }
  #pragma unroll
  for (int i = 0; i < 8; i++) {
    hx[lane*HSTR + ob0 + 2*i]   = fmaxf(acc[i].x, 0.f);
    hx[lane*HSTR + ob0 + 2*i+1] = fmaxf(acc[i].y, 0.f);
  }
  __syncthreads();

  // ---- layer 4 + tanh (wave 0 only) ----
  if (p == 0) {
    #pragma unroll
    for (int k = 0; k < 64; k++) h[k] = hx[lane*HSTR + k];
    v2f o4a = ld2(bf4), o4b = ld2(bf4 + 2);
    #pragma unroll
    for (int k = 0; k < 64; k++) {
      v2f hk = {h[k], h[k]};
      o4a = fma2(hk, ld2(W4 + k*4),     o4a);
      o4b = fma2(hk, ld2(W4 + k*4 + 2), o4b);
    }
    ((float4*)out)[b] = make_float4(fast_tanh(o4a.x), fast_tanh(o4a.y),
                                    fast_tanh(o4b.x), fast_tanh(o4b.y));
  }
}

extern "C" void kernel_launch(void* const* d_in, const int* in_sizes, int n_in,
                              void* d_out, int out_size, void* d_ws, size_t ws_size,
                              hipStream_t stream) {
  const float* x   = (const float*)d_in[0];
  const float* obs = (const float*)d_in[1];
  // d_in[2..4] = src/dst/node_seg: fixed star graph, exploited structurally
  const float* Wp1 = (const float*)d_in[5];
  const float* bp1 = (const float*)d_in[6];
  const float* Ws1 = (const float*)d_in[7];
  const float* Wn1 = (const float*)d_in[8];
  const float* bc1 = (const float*)d_in[9];
  const float* Wp2 = (const float*)d_in[10];
  const float* bp2 = (const float*)d_in[11];
  const float* Ws2 = (const float*)d_in[12];
  const float* Wn2 = (const float*)d_in[13];
  const float* bc2 = (const float*)d_in[14];
  const float* W1  = (const float*)d_in[15];
  const float* bf1 = (const float*)d_in[16];
  const float* W2  = (const float*)d_in[17];
  const float* bf2 = (const float*)d_in[18];
  const float* W3  = (const float*)d_in[19];
  const float* bf3 = (const float*)d_in[20];
  const float* W4  = (const float*)d_in[21];
  const float* bf4 = (const float*)d_in[22];
  float* res = (float*)d_ws;  // [65536][16] floats = 4 MB
  float* out = (float*)d_out;

  // 65536 batches / (4 waves/block * NB=4 batches/wave) = 4096 blocks
  hipLaunchKernelGGL(conv_kernel, dim3(4096), dim3(256), 0, stream,
                     x, Wp1, bp1, Ws1, Wn1, bc1, Wp2, bp2, res);
  hipLaunchKernelGGL(mlp_kernel, dim3(1024), dim3(256), 0, stream,
                     res, obs, Ws2, Wn2, bc2, W1, bf1, W2, bf2, W3, bf3, W4, bf4, out);
}

// Round 9
// 310.994 us; speedup vs baseline: 1.5868x; 1.1083x over previous
//
#include <hip/hip_runtime.h>

// Two kernels, no setup kernel, no weight blob.
// K1 conv (v8 = v7 minus software prefetch, (256,4)): lane = 8*c + g
//   (c = channel 0..7, g = node-group 0..7); each lane owns channel c of
//   nodes {g+8s}, s=0..3. Weights register-resident (48 floats/lane,
//   amortized over NB=4 batches). Per batch (2KB): wave loads 2 coalesced
//   dwordx4 per lane straight into LDS (no prefetch regs -- that 8-VGPR
//   buffer is what made v7 miss the 64-reg cap), node stride XSTR=20 ->
//   ds_read_b128 g-windows disjoint mod 32 = conflict-free; channel-
//   duplicate lanes broadcast (free). Node numbering n=g+8s makes
//   h-transpose reads (HPAD=12) conflict-free (12g%32 distinct).
//   Reductions: local serial + one 3-stage xor-butterfly per tree serving
//   all 8 channels. Star fold: leaves' agg is the wave-uniform m[node0]
//   vector via tiny LDS scr exchange. Same-wave LDS write->read (no
//   barriers) is in-order in the DS pipe (validated rounds 3/5).
//   VGPR/OCCUPANCY HISTORY (hard-won): natural VGPR=68. (256,3): 68 regs,
//   no spill, 9.2 waves/CU, 96us (latency-bound). (256,4): cap is 64 ->
//   clamped 68->64 + ~100MB scratch, 117us. (256,6): cap 40 -> ~1GB
//   scratch, 274us. gfx950 per-wave caps at waves/EU={3,4,6} are
//   {>68,64,40}. Fix = genuinely fit 64: drop prefetch (saves 8 regs),
//   rely on 16 waves/CU TLP to hide the load->LDS chain.
//   Writes res[B][16] = {sum_h[8], sum_agg2[8]} to d_ws.
// K2 mlp: unchanged known-good version. block = 64 batches x 4 waves, wave p
//   computes out-slice [16p,16p+16); pooled = (res@[Ws2|Wn2])/32 + bc2.

typedef float v2f __attribute__((ext_vector_type(2)));
__device__ __forceinline__ v2f fma2(v2f a, v2f b, v2f c) {
  return __builtin_elementwise_fma(a, b, c);
}
__device__ __forceinline__ v2f ld2(const float* p) { return *(const v2f*)p; }

__device__ __forceinline__ float fast_tanh(float v) {
  v = fminf(fmaxf(v, -10.f), 10.f);
  float e = exp2f(v * 2.8853900817779268f);          // e^(2v)
  return 1.f - 2.f * __builtin_amdgcn_rcpf(e + 1.f); // (e-1)/(e+1)
}

// ds_swizzle BitMode xor-butterfly within 8-lane blocks (and=0x1F keeps it
// inside 32-lane halves; xor masks 1,2,4 never cross an 8-block).
template<int OFF>
__device__ __forceinline__ float swz(float v) {
  return __int_as_float(__builtin_amdgcn_ds_swizzle(__float_as_int(v), OFF));
}
__device__ __forceinline__ float bflymax8(float t) {
  t = fmaxf(t, swz<0x041F>(t));  // xor 1
  t = fmaxf(t, swz<0x081F>(t));  // xor 2
  t = fmaxf(t, swz<0x101F>(t));  // xor 4
  return t;
}
__device__ __forceinline__ float bflysum8(float t) {
  t += swz<0x041F>(t);
  t += swz<0x081F>(t);
  t += swz<0x101F>(t);
  return t;
}

// ===================== K1: conv1 + conv2 + per-batch pooling ================
#define NB 4     // batches per wave
#define XSTR 20  // x-stage node stride (floats): 20g%32 distinct, 16B-aligned
#define HPAD 12  // h-transpose node stride: 12g%32 distinct, 16B-aligned
#define WREG (32*XSTR + 32*HPAD + 16)  // 1040 floats per wave
__global__ __launch_bounds__(256, 4) void conv_kernel(
    const float* __restrict__ x,
    const float* __restrict__ Wp1, const float* __restrict__ bp1,
    const float* __restrict__ Ws1, const float* __restrict__ Wn1,
    const float* __restrict__ bc1,
    const float* __restrict__ Wp2, const float* __restrict__ bp2,
    float* __restrict__ res) {
  __shared__ __align__(16) float lds[4 * WREG];
  const int tid  = threadIdx.x;
  const int wid  = tid >> 6;
  const int lane = tid & 63;
  const int c    = lane >> 3;     // channel 0..7
  const int g    = lane & 7;      // node-group: nodes g+8s, s=0..3
  const bool g0  = (g == 0);      // slot 0 of g==0 is node0
  float* xs  = lds + wid * WREG;  // [32 nodes][XSTR]
  float* hs  = xs + 32 * XSTR;    // [32 nodes][HPAD]
  float* scr = hs + 32 * HPAD;    // [16]

  // ---- weight preload: column c, register-resident for all NB batches ----
  float wp1[16], ws1[16], wn1[8], wp2[8];
  #pragma unroll
  for (int f = 0; f < 16; f++) { wp1[f] = Wp1[f*8 + c]; ws1[f] = Ws1[f*8 + c]; }
  #pragma unroll
  for (int j = 0; j < 8; j++)  { wn1[j] = Wn1[j*8 + c]; wp2[j] = Wp2[j*8 + c]; }
  const float bp1c = bp1[c], bc1c = bc1[c], bp2c = bp2[c];

  const int b0 = (blockIdx.x * 4 + wid) * NB;
  const float4* xg = (const float4*)x;      // 128 float4 per batch (2KB)
  size_t gb = (size_t)b0 * 128 + lane;

  #pragma unroll 1
  for (int it = 0; it < NB; ++it) {
    const int b = b0 + it;

    // load + stage to LDS (no prefetch regs): float4 j = lane+64k ->
    // node j>>2 (0..31), quad j&3; write banks (20n+4q)%32 <=2-way (free)
    #pragma unroll
    for (int k = 0; k < 2; k++) {
      float4 v = xg[gb + 64*k];
      const int j = lane + 64*k;
      *(float4*)(xs + (j >> 2) * XSTR + 4*(j & 3)) = v;
    }
    gb += 128;

    // conv1 for own 4 nodes (channel c): m=relu(x.wp1+b), sv=x.ws1+b
    float m[4], sv[4];
    #pragma unroll
    for (int s = 0; s < 4; s++) {
      const float* xn = xs + (g + 8*s) * XSTR;   // start bank 20g%32: distinct
      float4 X0 = *(const float4*)(xn);
      float4 X1 = *(const float4*)(xn + 4);
      float4 X2 = *(const float4*)(xn + 8);
      float4 X3 = *(const float4*)(xn + 12);
      float xfl[16] = {X0.x,X0.y,X0.z,X0.w, X1.x,X1.y,X1.z,X1.w,
                       X2.x,X2.y,X2.z,X2.w, X3.x,X3.y,X3.z,X3.w};
      float mm = bp1c, ss = bc1c;
      #pragma unroll
      for (int f = 0; f < 16; f++) {
        mm = fmaf(xfl[f], wp1[f], mm);
        ss = fmaf(xfl[f], ws1[f], ss);
      }
      m[s]  = fmaxf(mm, 0.f);
      sv[s] = ss;
    }

    // max over leaves (own channel): exclude node0 (slot 0 at g==0)
    float lm = g0 ? fmaxf(fmaxf(m[1], m[2]), m[3])
                  : fmaxf(fmaxf(m[0], m[1]), fmaxf(m[2], m[3]));
    lm = bflymax8(lm);

    // gather {m0_c, maxleaves_c} across channels via tiny LDS scratch
    if (g0) *(v2f*)(scr + 2*c) = (v2f){m[0], lm};
    float4 q0 = *(const float4*)(scr + 0);
    float4 q1 = *(const float4*)(scr + 4);
    float4 q2 = *(const float4*)(scr + 8);
    float4 q3 = *(const float4*)(scr + 12);
    float m0v[8] = {q0.x,q0.z, q1.x,q1.z, q2.x,q2.z, q3.x,q3.z};
    float mlv[8] = {q0.y,q0.w, q1.y,q1.w, q2.y,q2.w, q3.y,q3.w};

    // star fold: every leaf's agg = m0v (wave-uniform); node0's agg = mlv
    float leafdot = 0.f, zerodot = 0.f;
    #pragma unroll
    for (int j = 0; j < 8; j++) {
      leafdot = fmaf(m0v[j], wn1[j], leafdot);
      zerodot = fmaf(mlv[j], wn1[j], zerodot);
    }
    float h0 = fast_tanh(sv[0] + (g0 ? zerodot : leafdot));  // node g (0 if g0)
    float h1 = fast_tanh(sv[1] + leafdot);
    float h2 = fast_tanh(sv[2] + leafdot);
    float h3 = fast_tanh(sv[3] + leafdot);

    // h transpose via LDS: hs[n*HPAD + c]; write banks (12g+c)%32 <=2-way
    hs[(g +  0)*HPAD + c] = h0;
    hs[(g +  8)*HPAD + c] = h1;
    hs[(g + 16)*HPAD + c] = h2;
    hs[(g + 24)*HPAD + c] = h3;

    // conv2 pool-proj: m2[s] = relu(h_n . wp2 + bp2c); reads conflict-free
    float m2[4];
    #pragma unroll
    for (int s = 0; s < 4; s++) {
      const float* hn = hs + (g + 8*s) * HPAD;   // start bank 12g%32: distinct
      float4 ha = *(const float4*)(hn);
      float4 hb = *(const float4*)(hn + 4);
      float mm = bp2c;
      mm = fmaf(ha.x, wp2[0], mm); mm = fmaf(ha.y, wp2[1], mm);
      mm = fmaf(ha.z, wp2[2], mm); mm = fmaf(ha.w, wp2[3], mm);
      mm = fmaf(hb.x, wp2[4], mm); mm = fmaf(hb.y, wp2[5], mm);
      mm = fmaf(hb.z, wp2[6], mm); mm = fmaf(hb.w, wp2[7], mm);
      m2[s] = fmaxf(mm, 0.f);
    }

    // per-batch outputs (one butterfly serves all channels)
    float sh = bflysum8((h0 + h1) + (h2 + h3));          // sum_n h_c
    float lm2 = g0 ? fmaxf(fmaxf(m2[1], m2[2]), m2[3])
                   : fmaxf(fmaxf(m2[0], m2[1]), fmaxf(m2[2], m2[3]));
    lm2 = bflymax8(lm2);                                 // max over leaves' m2
    if (g0) {
      res[(size_t)b*16 + c]     = sh;
      res[(size_t)b*16 + 8 + c] = fmaf(31.f, m2[0], lm2); // + 31*m2[node0]
    }
  }
}

// ===================== K2: pooled fold + 4-layer MLP ========================
#define HSTR 65  // LDS row stride: (l*65+k)%32 distinct over 32 lanes; 2-way=free
__global__ __launch_bounds__(256, 3) void mlp_kernel(
    const float* __restrict__ res, const float* __restrict__ obs,
    const float* __restrict__ Ws2, const float* __restrict__ Wn2,
    const float* __restrict__ bc2,
    const float* __restrict__ W1, const float* __restrict__ bf1,
    const float* __restrict__ W2, const float* __restrict__ bf2,
    const float* __restrict__ W3, const float* __restrict__ bf3,
    const float* __restrict__ W4, const float* __restrict__ bf4,
    float* __restrict__ out) {
  __shared__ float hx[64 * HSTR];
  const int tid  = threadIdx.x;
  const int lane = tid & 63;                                  // batch in block
  const int p    = __builtin_amdgcn_readfirstlane(tid >> 6);  // out-slice wave
  const int b    = blockIdx.x * 64 + lane;
  const int ob0  = p * 16;

  const float4* rp = (const float4*)(res + (size_t)b * 16);
  float4 r0 = rp[0], r1 = rp[1], r2 = rp[2], r3 = rp[3];
  const float4* op = (const float4*)(obs + (size_t)b * 16);
  float4 o0 = op[0], o1 = op[1], o2 = op[2], o3 = op[3];
  float rm[8] = {r0.x,r0.y,r0.z,r0.w, r1.x,r1.y,r1.z,r1.w};
  float ag[8] = {r2.x,r2.y,r2.z,r2.w, r3.x,r3.y,r3.z,r3.w};
  float ob[16] = {o0.x,o0.y,o0.z,o0.w, o1.x,o1.y,o1.z,o1.w,
                  o2.x,o2.y,o2.z,o2.w, o3.x,o3.y,o3.z,o3.w};

  // pooled = (sumh@Ws2 + sumagg2@Wn2)/32 + bc2
  v2f pv[4];
  #pragma unroll
  for (int i = 0; i < 4; i++) pv[i] = (v2f){0.f, 0.f};
  #pragma unroll
  for (int j = 0; j < 8; j++) {
    v2f rv = {rm[j], rm[j]}, av = {ag[j], ag[j]};
    #pragma unroll
    for (int i = 0; i < 4; i++) {
      pv[i] = fma2(rv, ld2(Ws2 + j*8 + 2*i), pv[i]);
      pv[i] = fma2(av, ld2(Wn2 + j*8 + 2*i), pv[i]);
    }
  }
  float pooled[8];
  #pragma unroll
  for (int i = 0; i < 4; i++) {
    pooled[2*i]   = fmaf(pv[i].x, 1.f/32.f, bc2[2*i]);
    pooled[2*i+1] = fmaf(pv[i].y, 1.f/32.f, bc2[2*i+1]);
  }

  v2f acc[8];
  // ---- layer 1: [pooled | obs] @ W1 + bf1, slice [ob0, ob0+16) ----
  #pragma unroll
  for (int i = 0; i < 8; i++) acc[i] = ld2(bf1 + ob0 + 2*i);
  #pragma unroll
  for (int j = 0; j < 8; j++) {
    v2f sj = {pooled[j], pooled[j]};
    #pragma unroll
    for (int i = 0; i < 8; i++) acc[i] = fma2(sj, ld2(W1 + j*64 + ob0 + 2*i), acc[i]);
  }
  #pragma unroll
  for (int j = 0; j < 16; j++) {
    v2f sj = {ob[j], ob[j]};
    #pragma unroll
    for (int i = 0; i < 8; i++) acc[i] = fma2(sj, ld2(W1 + (8+j)*64 + ob0 + 2*i), acc[i]);
  }
  #pragma unroll
  for (int i = 0; i < 8; i++) {
    hx[lane*HSTR + ob0 + 2*i]   = fmaxf(acc[i].x, 0.f);
    hx[lane*HSTR + ob0 + 2*i+1] = fmaxf(acc[i].y, 0.f);
  }
  __syncthreads();
  float h[64];
  #pragma unroll
  for (int k = 0; k < 64; k++) h[k] = hx[lane*HSTR + k];
  __syncthreads();

  // ---- layer 2 ----
  #pragma unroll
  for (int i = 0; i < 8; i++) acc[i] = ld2(bf2 + ob0 + 2*i);
  #pragma unroll
  for (int k = 0; k < 64; k++) {
    v2f hk = {h[k], h[k]};
    #pragma unroll
    for (int i = 0; i < 8; i++) acc[i] = fma2(hk, ld2(W2 + k*64 + ob0 + 2*i), acc[i]);
  }
  #pragma unroll
  for (int i = 0; i < 8; i++) {
    hx[lane*HSTR + ob0 + 2*i]   = fmaxf(acc[i].x, 0.f);
    hx[lane*HSTR + ob0 + 2*i+1] = fmaxf(acc[i].y, 0.f);
  }
  __syncthreads();
  #pragma unroll
  for (int k = 0; k < 64; k++) h[k] = hx[lane*HSTR + k];
  __syncthreads();

  // ---- layer 3 ----
  #pragma unroll
  for (int i = 0; i < 8; i++) acc[i] = ld2(bf3 + ob0 + 2*i);
  #pragma unroll
  for (int k = 0; k < 64; k++) {
    v2f hk = {h[k], h[k]};
    #pragma unroll
    for (int i = 0; i < 8; i++) acc[i] = fma2(hk, ld2(W3 + k*64 + ob0 + 2*i), acc[i]);
  }
  #pragma unroll
  for (int i = 0; i < 8; i++) {
    hx[lane*HSTR + ob0 + 2*i]   = fmaxf(acc[i].x, 0.f);
    hx[lane*HSTR + ob0 + 2*i+1] = fmaxf(acc[i].y, 0.f);
  }
  __syncthreads();

  // ---- layer 4 + tanh (wave 0 only) ----
  if (p == 0) {
    #pragma unroll
    for (int k = 0; k < 64; k++) h[k] = hx[lane*HSTR + k];
    v2f o4a = ld2(bf4), o4b = ld2(bf4 + 2);
    #pragma unroll
    for (int k = 0; k < 64; k++) {
      v2f hk = {h[k], h[k]};
      o4a = fma2(hk, ld2(W4 + k*4),     o4a);
      o4b = fma2(hk, ld2(W4 + k*4 + 2), o4b);
    }
    ((float4*)out)[b] = make_float4(fast_tanh(o4a.x), fast_tanh(o4a.y),
                                    fast_tanh(o4b.x), fast_tanh(o4b.y));
  }
}

extern "C" void kernel_launch(void* const* d_in, const int* in_sizes, int n_in,
                              void* d_out, int out_size, void* d_ws, size_t ws_size,
                              hipStream_t stream) {
  const float* x   = (const float*)d_in[0];
  const float* obs = (const float*)d_in[1];
  // d_in[2..4] = src/dst/node_seg: fixed star graph, exploited structurally
  const float* Wp1 = (const float*)d_in[5];
  const float* bp1 = (const float*)d_in[6];
  const float* Ws1 = (const float*)d_in[7];
  const float* Wn1 = (const float*)d_in[8];
  const float* bc1 = (const float*)d_in[9];
  const float* Wp2 = (const float*)d_in[10];
  const float* bp2 = (const float*)d_in[11];
  const float* Ws2 = (const float*)d_in[12];
  const float* Wn2 = (const float*)d_in[13];
  const float* bc2 = (const float*)d_in[14];
  const float* W1  = (const float*)d_in[15];
  const float* bf1 = (const float*)d_in[16];
  const float* W2  = (const float*)d_in[17];
  const float* bf2 = (const float*)d_in[18];
  const float* W3  = (const float*)d_in[19];
  const float* bf3 = (const float*)d_in[20];
  const float* W4  = (const float*)d_in[21];
  const float* bf4 = (const float*)d_in[22];
  float* res = (float*)d_ws;  // [65536][16] floats = 4 MB
  float* out = (float*)d_out;

  // 65536 batches / (4 waves/block * NB=4 batches/wave) = 4096 blocks
  hipLaunchKernelGGL(conv_kernel, dim3(4096), dim3(256), 0, stream,
                     x, Wp1, bp1, Ws1, Wn1, bc1, Wp2, bp2, res);
  hipLaunchKernelGGL(mlp_kernel, dim3(1024), dim3(256), 0, stream,
                     res, obs, Ws2, Wn2, bc2, W1, bf1, W2, bf2, W3, bf3, W4, bf4, out);
}